// Round 5
// baseline (325.301 us; speedup 1.0000x reference)
//
#include <hip/hip_runtime.h>

// VectorQuantizer: inputs [32,256,2048] f32, weight [1024,256] f32
// out0 = quantized [32,256,2048] f32, out1 = argmin indices [65536] (as f32)
//
// Round 5: X-prep FUSED into the MFMA kernel (each block splits its own
// 128-t tile into ws, then K-loops over it; self-region only -> no
// cross-block dependency). xnorm stays in LDS. wprep widened to 64 blocks
// with coalesced f16x4 stores. K-loop is byte-identical to verified round 4:
//   dist = fp32( fp32(xnorm + wnorm) - fp32(2*dot) ),
//   dot = fp16x2-split 3-product MFMA, W pre-scaled by 1024, lo terms * 2^24,
//   double-buffered single-barrier staging via global_load_lds(16B).

#define VQ_B   32
#define VQ_D   256
#define VQ_T   2048
#define VQ_K   1024

typedef _Float16 f16x8 __attribute__((ext_vector_type(8)));
typedef _Float16 f16x4 __attribute__((ext_vector_type(4)));
typedef float    f32x4 __attribute__((ext_vector_type(4)));

#define GLOAD_LDS16(gaddr, laddr) \
  __builtin_amdgcn_global_load_lds((const __attribute__((address_space(1))) void*)(gaddr), \
                                   (__attribute__((address_space(3))) void*)(laddr), 16, 0, 0)

// ---------------- kernel 1: W norms (f64) + fp16x2 split, 64 blocks.
// Block handles 16 k-rows; thread (kk = tid>>4, dg = tid&15) converts 16 d.
// Stores are f16x4 (8B/lane, 128B contiguous per 16-lane row segment).
// wnorm: per-dg partials combined in FIXED dg order (deterministic).
__global__ __launch_bounds__(256) void vq_wprep_kernel(
    const float* __restrict__ w, float* __restrict__ wnorm,
    _Float16* __restrict__ Wh, _Float16* __restrict__ Wl) {
    __shared__ double ws_[16][16];
    const int tid = threadIdx.x;
    const int kk  = tid >> 4;
    const int dg  = tid & 15;
    const int k   = blockIdx.x * 16 + kk;
    const float* src = w + (size_t)k * VQ_D + dg * 16;
    double s = 0.0;
    #pragma unroll
    for (int q = 0; q < 4; ++q) {
        float4 v = *(const float4*)(src + q * 4);
        s += (double)v.x * v.x + (double)v.y * v.y
           + (double)v.z * v.z + (double)v.w * v.w;
        const float e4[4] = {v.x, v.y, v.z, v.w};
        f16x4 hv, lv;
        #pragma unroll
        for (int j = 0; j < 4; ++j) {
            const float es = e4[j] * 1024.0f;            // exact pow2 scale
            const _Float16 h = (_Float16)es;
            hv[j] = h;
            lv[j] = (_Float16)((es - (float)h) * 16777216.0f);
        }
        *(f16x4*)(Wh + (size_t)k * VQ_D + dg * 16 + q * 4) = hv;
        *(f16x4*)(Wl + (size_t)k * VQ_D + dg * 16 + q * 4) = lv;
    }
    ws_[kk][dg] = s;
    __syncthreads();
    if (dg == 0) {
        double acc = 0.0;
        #pragma unroll
        for (int g = 0; g < 16; ++g) acc += ws_[kk][g];  // fixed order
        wnorm[k] = (float)acc;
    }
}

// ---------------- kernel 2: fused X-split prologue + MFMA GEMM + argmin + gather
// 512 blocks, 4 waves (2x2), 128t x 128k tile, 64 linear (k0,d0) steps,
// double-buffered 2x32KB staging, one barrier per step.
__global__ __launch_bounds__(256, 2) void vq_mfma_kernel(
    const float* __restrict__ inp,
    const _Float16* __restrict__ Wh, const _Float16* __restrict__ Wl,
    _Float16* __restrict__ Xh, _Float16* __restrict__ Xl,
    const float* __restrict__ wnorm,
    const float* __restrict__ w,
    float* __restrict__ outq, float* __restrict__ outi)
{
    __shared__ alignas(16) char stg[2][32768];   // 2 x 32 regions x 1024 B
    const int tid  = threadIdx.x;
    const int lane = tid & 63;
    const int wv   = tid >> 6;                // wave 0..3
    const int m16  = lane & 15;
    const int quad = lane >> 4;
    const int wm   = wv & 1;                  // k half (waves 0/1), lo/hi sel
    const int wn   = wv >> 1;                 // t half
    const int b    = blockIdx.x >> 4;
    const int tt0  = (blockIdx.x & 15) * 128;
    const long bt  = (long)b * VQ_T + tt0;

    // ======== PROLOGUE: split this block's own X tile into ws (chunk layout
    // Xh[((b*32+dc)*2048 + t)*8 + j]), xnorm in LDS. Same numerics as r4:
    // f64 sum, half0 + half1 order; f16x2 split with 2^24-scaled lo.
    {
        const int t    = tid & 127;
        const int half = tid >> 7;
        const float* p = inp + (size_t)b * VQ_D * VQ_T + tt0 + t;
        double s = 0.0;
        #pragma unroll 4
        for (int dc = half * 16; dc < half * 16 + 16; ++dc) {
            float x[8];
            #pragma unroll
            for (int j = 0; j < 8; ++j)
                x[j] = p[(size_t)(dc * 8 + j) * VQ_T];   // 256B coalesced/wave
            f16x8 hv, lv;
            #pragma unroll
            for (int j = 0; j < 8; ++j) {
                s += (double)x[j] * (double)x[j];        // sequential-d f64
                const _Float16 h = (_Float16)x[j];
                hv[j] = h;
                lv[j] = (_Float16)((x[j] - (float)h) * 16777216.0f);
            }
            const size_t off = (((size_t)b * 32 + dc) * VQ_T + tt0 + t) * 8;
            *(f16x8*)(Xh + off) = hv;                    // 1KB contiguous/wave
            *(f16x8*)(Xl + off) = lv;
        }
        double* ps  = (double*)stg[0];                   // [128]
        float*  xns = (float*)(stg[0] + 1024);           // [128]
        if (half) ps[t] = s;
        __threadfence();        // drain global stores; L1 inv -> reads see L2
        __syncthreads();
        if (!half) xns[t] = (float)(s + ps[t]);          // r4 order: h0 + h1
        __syncthreads();
        // nothing else: xnr read below, then stg reused by staging
    }

    // xnorm for this lane's 4 t-columns (from LDS)
    float xnr[4];
    {
        const float* xns = (const float*)(stg[0] + 1024);
        #pragma unroll
        for (int fn = 0; fn < 4; ++fn)
            xnr[fn] = xns[wn * 64 + fn * 16 + m16];
    }
    __syncthreads();            // xns consumed; stg[0] free for staging

    // 8 staging source pointers per wave: wave0=Wh, wave1=Wl, wave2=Xh, wave3=Xl
    const char* gp[8];
    #pragma unroll
    for (int i = 0; i < 8; ++i) {
        const int hf = i >> 2, f = i & 3;
        if (wv < 2) {
            const char* baseW = (const char*)((wv & 1) ? Wl : Wh);
            gp[i] = baseW + (size_t)(hf * 64 + f * 16 + m16) * 512 + quad * 16;
        } else {
            const char* baseX = (const char*)((wv & 1) ? Xl : Xh);
            // chunk layout: byte addr = ((b*32 + dc0+quad)*2048 + t_row)*16
            gp[i] = baseX + (((size_t)b * 32 + quad) * 2048
                             + (tt0 + hf * 64 + f * 16 + m16)) * 16;
        }
    }
    // advance after issuing step q: W +64B (32 halves), X +4 dchunks;
    // at chunk boundary W jumps k0+=128 and rewinds d, X rewinds d.
    auto advance = [&](int q) {
        if ((q & 7) == 7) {
            #pragma unroll
            for (int i = 0; i < 8; ++i)
                gp[i] += (wv < 2) ? (long)(65536 - 448) : (long)(-7) * 131072;
        } else {
            #pragma unroll
            for (int i = 0; i < 8; ++i)
                gp[i] += (wv < 2) ? 64L : 131072L;
        }
    };

    float bestv[4] = {3.0e38f, 3.0e38f, 3.0e38f, 3.0e38f};
    int   besti[4] = {0, 0, 0, 0};
    f32x4 acch[4][4], accl[4][4];

    // prologue: issue step 0 into buffer 0
    #pragma unroll
    for (int i = 0; i < 8; ++i)
        GLOAD_LDS16(gp[i], &stg[0][(wv * 8 + i) * 1024]);
    advance(0);

    for (int s = 0; s < 64; ++s) {
        const int cur = s & 1;
        if ((s & 7) == 0) {
            #pragma unroll
            for (int fm = 0; fm < 4; ++fm)
                #pragma unroll
                for (int fn = 0; fn < 4; ++fn) {
                    acch[fm][fn] = (f32x4){0.f, 0.f, 0.f, 0.f};
                    accl[fm][fn] = (f32x4){0.f, 0.f, 0.f, 0.f};
                }
        }
        __syncthreads();            // drains vmcnt -> stg[cur] resident
        if (s < 63) {               // prefetch step s+1 into the other buffer
            #pragma unroll
            for (int i = 0; i < 8; ++i)
                GLOAD_LDS16(gp[i], &stg[cur ^ 1][(wv * 8 + i) * 1024]);
            advance(s + 1);
        }

        const char* base = stg[cur];
        f16x8 ah[4], al[4], bh[4], bl[4];
        #pragma unroll
        for (int f = 0; f < 4; ++f) {
            ah[f] = *(const f16x8*)(base + ((wm * 4 + f)) * 1024 + lane * 16);
            al[f] = *(const f16x8*)(base + ((8 + wm * 4 + f)) * 1024 + lane * 16);
            bh[f] = *(const f16x8*)(base + ((16 + wn * 4 + f)) * 1024 + lane * 16);
            bl[f] = *(const f16x8*)(base + ((24 + wn * 4 + f)) * 1024 + lane * 16);
        }
        #pragma unroll
        for (int fm = 0; fm < 4; ++fm)
            #pragma unroll
            for (int fn = 0; fn < 4; ++fn) {
                acch[fm][fn] = __builtin_amdgcn_mfma_f32_16x16x32_f16(
                    ah[fm], bh[fn], acch[fm][fn], 0, 0, 0);
                accl[fm][fn] = __builtin_amdgcn_mfma_f32_16x16x32_f16(
                    ah[fm], bl[fn], accl[fm][fn], 0, 0, 0);
                accl[fm][fn] = __builtin_amdgcn_mfma_f32_16x16x32_f16(
                    al[fm], bh[fn], accl[fm][fn], 0, 0, 0);
            }

        if ((s & 7) == 7) {
            const int k0 = (s >> 3) * 128;
            // scores, reference fp32 rounding chain; strict '<' over ascending
            // k => ties resolve to lowest index (matches np.argmin)
            #pragma unroll
            for (int fm = 0; fm < 4; ++fm) {
                #pragma unroll
                for (int r = 0; r < 4; ++r) {
                    const int kg = k0 + wm * 64 + fm * 16 + quad * 4 + r;
                    const float wnk = wnorm[kg];
                    #pragma unroll
                    for (int fn = 0; fn < 4; ++fn) {
                        const float t1 = xnr[fn] + wnk;
                        const float d2 = (acch[fm][fn][r]
                                          + accl[fm][fn][r] * 5.9604644775390625e-8f)
                                         * 0.001953125f;
                        const float sc = t1 - d2;
                        if (sc < bestv[fn]) { bestv[fn] = sc; besti[fn] = kg; }
                    }
                }
            }
        }
    }

    // cross-lane argmin: lanes {c, c+16, c+32, c+48} share a t-column
    float rv[4]; int ri[4];
    #pragma unroll
    for (int fn = 0; fn < 4; ++fn) {
        float bv = bestv[fn]; int bi = besti[fn];
        #pragma unroll
        for (int mask = 16; mask <= 32; mask <<= 1) {
            const float ov = __shfl_xor(bv, mask, 64);
            const int   oi = __shfl_xor(bi, mask, 64);
            if (ov < bv || (ov == bv && oi < bi)) { bv = ov; bi = oi; }
        }
        rv[fn] = bv; ri[fn] = bi;
    }

    // cross-wave (wm 0 vs 1) reduce via LDS overlay
    __syncthreads();
    float* sv = (float*)stg[0];              // [2][128]
    int*   si = (int*)(stg[0] + 1024);       // [2][128]
    if (quad == 0) {
        #pragma unroll
        for (int fn = 0; fn < 4; ++fn) {
            const int tl = wn * 64 + fn * 16 + m16;
            sv[wm * 128 + tl] = rv[fn];
            si[wm * 128 + tl] = ri[fn];
        }
    }
    __syncthreads();
    if (tid < 128) {
        const float v0 = sv[tid], v1 = sv[128 + tid];
        const int   i0 = si[tid], i1 = si[128 + tid];
        const int   bi = (v1 < v0 || (v1 == v0 && i1 < i0)) ? i1 : i0;
        si[tid] = bi;
        outi[bt + tid] = (float)bi;
    }
    __syncthreads();

    // quantized output: outq[b][d][t] = w[best[t]][d]  (verified epilogue)
    {
        const int t  = tid & 127;
        const int dh = tid >> 7;
        const int bi = si[t];
        const float* wrow = w + (size_t)bi * VQ_D + dh * 128;
        float* obase = outq + ((size_t)b * VQ_D + (size_t)dh * 128) * VQ_T + tt0 + t;
        #pragma unroll 4
        for (int dd = 0; dd < 128; dd += 4) {
            float4 v = *(const float4*)(wrow + dd);
            obase[(size_t)(dd + 0) * VQ_T] = v.x;
            obase[(size_t)(dd + 1) * VQ_T] = v.y;
            obase[(size_t)(dd + 2) * VQ_T] = v.z;
            obase[(size_t)(dd + 3) * VQ_T] = v.w;
        }
    }
}

extern "C" void kernel_launch(void* const* d_in, const int* in_sizes, int n_in,
                              void* d_out, int out_size, void* d_ws, size_t ws_size,
                              hipStream_t stream) {
    const float* inp = (const float*)d_in[0];
    const float* w   = (const float*)d_in[1];
    float* outq  = (float*)d_out;
    float* outi  = outq + (size_t)VQ_B * VQ_D * VQ_T;   // indices appended flat

    float*    wnorm = (float*)d_ws;                     // [1024]
    _Float16* Wh    = (_Float16*)(wnorm + VQ_K);        // [1024*256]
    _Float16* Wl    = Wh + (size_t)VQ_K * VQ_D;
    _Float16* Xh    = Wl + (size_t)VQ_K * VQ_D;         // [65536*256], chunk layout
    _Float16* Xl    = Xh + (size_t)VQ_B * VQ_T * VQ_D;
    // total ws use: ~68.1 MB

    vq_wprep_kernel<<<dim3(VQ_K / 16), dim3(256), 0, stream>>>(w, wnorm, Wh, Wl);
    vq_mfma_kernel<<<dim3(VQ_B * (VQ_T / 128)), dim3(256), 0, stream>>>(
        inp, Wh, Wl, Xh, Xl, wnorm, w, outq, outi);
}

// Round 6
// 235.705 us; speedup vs baseline: 1.3801x; 1.3801x over previous
//
#include <hip/hip_runtime.h>

// VectorQuantizer: inputs [32,256,2048] f32, weight [1024,256] f32
// out0 = quantized [32,256,2048] f32, out1 = argmin indices [65536] (as f32)
//
// Round 6: revert to the verified round-4 structure (separate prep; main MFMA
// kernel byte-identical to round 4's 131.7us / MfmaUtil 34% version), with:
//  - wprep fixed (round-5's 64-block coalesced version; round-4's 4-block
//    scattered-2B-store version was ~100us at 1.5% GPU utilization)
//  - wprep + xprep merged into ONE 576-block launch so they overlap.
// Lesson from round 5: __threadfence() (device-scope release) on CDNA4 forces
// L2 writeback for cross-XCD visibility -> ~118us; never self-read-back
// freshly written global data behind a fence inside the hot kernel.
//
// Numerics (verified rounds 2-5): dist = fp32( fp32(xnorm+wnorm) - fp32(2dot) ),
// dot = fp16x2-split 3-product MFMA, W pre-scaled by 1024 (exact pow2),
// lo terms scaled 2^24; argmin strict '<' ascending k + index-min tie-break.

#define VQ_B   32
#define VQ_D   256
#define VQ_T   2048
#define VQ_K   1024

typedef _Float16 f16x8 __attribute__((ext_vector_type(8)));
typedef _Float16 f16x4 __attribute__((ext_vector_type(4)));
typedef float    f32x4 __attribute__((ext_vector_type(4)));

#define GLOAD_LDS16(gaddr, laddr) \
  __builtin_amdgcn_global_load_lds((const __attribute__((address_space(1))) void*)(gaddr), \
                                   (__attribute__((address_space(3))) void*)(laddr), 16, 0, 0)

// ---------------- kernel 1: merged prep, 576 blocks.
// blocks 0..511: X prep -> xnorm (f64, verified order) + fp16x2 split into
//   chunk layout Xh[((b*32+dc)*2048 + t)*8 + j]. Reads 256B/wave coalesced,
//   writes 1KB/wave contiguous.
// blocks 512..575: W prep -> wnorm (f64, fixed combine order) + fp16x2 split,
//   f16x4 coalesced stores (verified round 5).
__global__ __launch_bounds__(256) void vq_prep_kernel(
    const float* __restrict__ inp, const float* __restrict__ w,
    _Float16* __restrict__ Xh, _Float16* __restrict__ Xl,
    float* __restrict__ xnorm,
    float* __restrict__ wnorm,
    _Float16* __restrict__ Wh, _Float16* __restrict__ Wl)
{
    __shared__ double sbuf[256];
    const int tid = threadIdx.x;
    if (blockIdx.x < 512) {
        const int t    = tid & 127;
        const int half = tid >> 7;             // d half: 0 -> 0..127, 1 -> 128..255
        const int b    = blockIdx.x >> 4;
        const int tg   = (blockIdx.x & 15) * 128 + t;
        const float* p = inp + (size_t)b * VQ_D * VQ_T + tg;

        double s = 0.0;
        #pragma unroll 4
        for (int dc = half * 16; dc < half * 16 + 16; ++dc) {
            float x[8];
            #pragma unroll
            for (int j = 0; j < 8; ++j)
                x[j] = p[(size_t)(dc * 8 + j) * VQ_T];     // 256B coalesced/wave
            f16x8 hv, lv;
            #pragma unroll
            for (int j = 0; j < 8; ++j) {
                s += (double)x[j] * (double)x[j];          // sequential-d f64 order
                const _Float16 h = (_Float16)x[j];
                hv[j] = h;
                lv[j] = (_Float16)((x[j] - (float)h) * 16777216.0f);
            }
            const size_t off = (((size_t)b * 32 + dc) * VQ_T + tg) * 8;
            *(f16x8*)(Xh + off) = hv;                      // 1KB contiguous/wave
            *(f16x8*)(Xl + off) = lv;
        }
        if (half) sbuf[t] = s;
        __syncthreads();
        if (!half) xnorm[(size_t)b * VQ_T + tg] = (float)(s + sbuf[t]);
    } else {
        // W prep: block handles 16 k-rows; thread (kk=tid>>4, dg=tid&15)
        double (*ws_)[16] = (double(*)[16])sbuf;
        const int kk = tid >> 4;
        const int dg = tid & 15;
        const int k  = (blockIdx.x - 512) * 16 + kk;
        const float* src = w + (size_t)k * VQ_D + dg * 16;
        double s = 0.0;
        #pragma unroll
        for (int q = 0; q < 4; ++q) {
            float4 v = *(const float4*)(src + q * 4);
            s += (double)v.x * v.x + (double)v.y * v.y
               + (double)v.z * v.z + (double)v.w * v.w;
            const float e4[4] = {v.x, v.y, v.z, v.w};
            f16x4 hv, lv;
            #pragma unroll
            for (int j = 0; j < 4; ++j) {
                const float es = e4[j] * 1024.0f;          // exact pow2 scale
                const _Float16 h = (_Float16)es;
                hv[j] = h;
                lv[j] = (_Float16)((es - (float)h) * 16777216.0f);
            }
            *(f16x4*)(Wh + (size_t)k * VQ_D + dg * 16 + q * 4) = hv;
            *(f16x4*)(Wl + (size_t)k * VQ_D + dg * 16 + q * 4) = lv;
        }
        ws_[kk][dg] = s;
        __syncthreads();
        if (dg == 0) {
            double acc = 0.0;
            #pragma unroll
            for (int g = 0; g < 16; ++g) acc += ws_[kk][g];  // fixed order
            wnorm[k] = (float)acc;
        }
    }
}

// ---------------- kernel 2: MFMA distance GEMM + argmin + gather
// BYTE-IDENTICAL to round 4's verified 131.7us kernel.
// 512 blocks, 4 waves (2x2), 128t x 128k tile, 64 linear (k0,d0) steps,
// double-buffered 2x32KB staging, one barrier per step (loads for step s+1
// issued right after the barrier of step s -> vmcnt drain overlaps compute).
__global__ __launch_bounds__(256, 2) void vq_mfma_kernel(
    const _Float16* __restrict__ Wh, const _Float16* __restrict__ Wl,
    const _Float16* __restrict__ Xh, const _Float16* __restrict__ Xl,
    const float* __restrict__ wnorm, const float* __restrict__ xnorm,
    const float* __restrict__ w,
    float* __restrict__ outq, float* __restrict__ outi)
{
    __shared__ alignas(16) char stg[2][32768];   // 2 x 32 regions x 1024 B
    const int tid  = threadIdx.x;
    const int lane = tid & 63;
    const int wv   = tid >> 6;                // wave 0..3
    const int m16  = lane & 15;
    const int quad = lane >> 4;
    const int wm   = wv & 1;                  // k half (waves 0/1), lo/hi sel
    const int wn   = wv >> 1;                 // t half
    const int b    = blockIdx.x >> 4;
    const int tt0  = (blockIdx.x & 15) * 128;
    const long bt  = (long)b * VQ_T + tt0;

    // xnorm for this lane's 4 t-columns (constant across k)
    float xnr[4];
    #pragma unroll
    for (int fn = 0; fn < 4; ++fn)
        xnr[fn] = xnorm[bt + wn * 64 + fn * 16 + m16];

    // 8 staging source pointers per wave: wave0=Wh, wave1=Wl, wave2=Xh, wave3=Xl
    const char* gp[8];
    #pragma unroll
    for (int i = 0; i < 8; ++i) {
        const int hf = i >> 2, f = i & 3;
        if (wv < 2) {
            const char* baseW = (const char*)((wv & 1) ? Wl : Wh);
            gp[i] = baseW + (size_t)(hf * 64 + f * 16 + m16) * 512 + quad * 16;
        } else {
            const char* baseX = (const char*)((wv & 1) ? Xl : Xh);
            // chunk layout: byte addr = ((b*32 + dc0+quad)*2048 + t_row)*16
            gp[i] = baseX + (((size_t)b * 32 + quad) * 2048
                             + (tt0 + hf * 64 + f * 16 + m16)) * 16;
        }
    }
    // advance after issuing step q: W +64B (32 halves), X +4 dchunks;
    // at chunk boundary W jumps k0+=128 and rewinds d, X rewinds d.
    auto advance = [&](int q) {
        if ((q & 7) == 7) {
            #pragma unroll
            for (int i = 0; i < 8; ++i)
                gp[i] += (wv < 2) ? (long)(65536 - 448) : (long)(-7) * 131072;
        } else {
            #pragma unroll
            for (int i = 0; i < 8; ++i)
                gp[i] += (wv < 2) ? 64L : 131072L;
        }
    };

    float bestv[4] = {3.0e38f, 3.0e38f, 3.0e38f, 3.0e38f};
    int   besti[4] = {0, 0, 0, 0};
    f32x4 acch[4][4], accl[4][4];

    // prologue: issue step 0 into buffer 0
    #pragma unroll
    for (int i = 0; i < 8; ++i)
        GLOAD_LDS16(gp[i], &stg[0][(wv * 8 + i) * 1024]);
    advance(0);

    for (int s = 0; s < 64; ++s) {
        const int cur = s & 1;
        if ((s & 7) == 0) {
            #pragma unroll
            for (int fm = 0; fm < 4; ++fm)
                #pragma unroll
                for (int fn = 0; fn < 4; ++fn) {
                    acch[fm][fn] = (f32x4){0.f, 0.f, 0.f, 0.f};
                    accl[fm][fn] = (f32x4){0.f, 0.f, 0.f, 0.f};
                }
        }
        __syncthreads();            // drains vmcnt -> stg[cur] resident
        if (s < 63) {               // prefetch step s+1 into the other buffer
            #pragma unroll
            for (int i = 0; i < 8; ++i)
                GLOAD_LDS16(gp[i], &stg[cur ^ 1][(wv * 8 + i) * 1024]);
            advance(s + 1);
        }

        const char* base = stg[cur];
        f16x8 ah[4], al[4], bh[4], bl[4];
        #pragma unroll
        for (int f = 0; f < 4; ++f) {
            ah[f] = *(const f16x8*)(base + ((wm * 4 + f)) * 1024 + lane * 16);
            al[f] = *(const f16x8*)(base + ((8 + wm * 4 + f)) * 1024 + lane * 16);
            bh[f] = *(const f16x8*)(base + ((16 + wn * 4 + f)) * 1024 + lane * 16);
            bl[f] = *(const f16x8*)(base + ((24 + wn * 4 + f)) * 1024 + lane * 16);
        }
        #pragma unroll
        for (int fm = 0; fm < 4; ++fm)
            #pragma unroll
            for (int fn = 0; fn < 4; ++fn) {
                acch[fm][fn] = __builtin_amdgcn_mfma_f32_16x16x32_f16(
                    ah[fm], bh[fn], acch[fm][fn], 0, 0, 0);
                accl[fm][fn] = __builtin_amdgcn_mfma_f32_16x16x32_f16(
                    ah[fm], bl[fn], accl[fm][fn], 0, 0, 0);
                accl[fm][fn] = __builtin_amdgcn_mfma_f32_16x16x32_f16(
                    al[fm], bh[fn], accl[fm][fn], 0, 0, 0);
            }

        if ((s & 7) == 7) {
            const int k0 = (s >> 3) * 128;
            // scores, reference fp32 rounding chain; strict '<' over ascending
            // k => ties resolve to lowest index (matches np.argmin)
            #pragma unroll
            for (int fm = 0; fm < 4; ++fm) {
                #pragma unroll
                for (int r = 0; r < 4; ++r) {
                    const int kg = k0 + wm * 64 + fm * 16 + quad * 4 + r;
                    const float wnk = wnorm[kg];
                    #pragma unroll
                    for (int fn = 0; fn < 4; ++fn) {
                        const float t1 = xnr[fn] + wnk;
                        const float d2 = (acch[fm][fn][r]
                                          + accl[fm][fn][r] * 5.9604644775390625e-8f)
                                         * 0.001953125f;
                        const float sc = t1 - d2;
                        if (sc < bestv[fn]) { bestv[fn] = sc; besti[fn] = kg; }
                    }
                }
            }
        }
    }

    // cross-lane argmin: lanes {c, c+16, c+32, c+48} share a t-column
    float rv[4]; int ri[4];
    #pragma unroll
    for (int fn = 0; fn < 4; ++fn) {
        float bv = bestv[fn]; int bi = besti[fn];
        #pragma unroll
        for (int mask = 16; mask <= 32; mask <<= 1) {
            const float ov = __shfl_xor(bv, mask, 64);
            const int   oi = __shfl_xor(bi, mask, 64);
            if (ov < bv || (ov == bv && oi < bi)) { bv = ov; bi = oi; }
        }
        rv[fn] = bv; ri[fn] = bi;
    }

    // cross-wave (wm 0 vs 1) reduce via LDS overlay
    __syncthreads();
    float* sv = (float*)stg[0];              // [2][128]
    int*   si = (int*)(stg[0] + 1024);       // [2][128]
    if (quad == 0) {
        #pragma unroll
        for (int fn = 0; fn < 4; ++fn) {
            const int tl = wn * 64 + fn * 16 + m16;
            sv[wm * 128 + tl] = rv[fn];
            si[wm * 128 + tl] = ri[fn];
        }
    }
    __syncthreads();
    if (tid < 128) {
        const float v0 = sv[tid], v1 = sv[128 + tid];
        const int   i0 = si[tid], i1 = si[128 + tid];
        const int   bi = (v1 < v0 || (v1 == v0 && i1 < i0)) ? i1 : i0;
        si[tid] = bi;
        outi[bt + tid] = (float)bi;
    }
    __syncthreads();

    // quantized output: outq[b][d][t] = w[best[t]][d]  (verified epilogue)
    {
        const int t  = tid & 127;
        const int dh = tid >> 7;
        const int bi = si[t];
        const float* wrow = w + (size_t)bi * VQ_D + dh * 128;
        float* obase = outq + ((size_t)b * VQ_D + (size_t)dh * 128) * VQ_T + tt0 + t;
        #pragma unroll 4
        for (int dd = 0; dd < 128; dd += 4) {
            float4 v = *(const float4*)(wrow + dd);
            obase[(size_t)(dd + 0) * VQ_T] = v.x;
            obase[(size_t)(dd + 1) * VQ_T] = v.y;
            obase[(size_t)(dd + 2) * VQ_T] = v.z;
            obase[(size_t)(dd + 3) * VQ_T] = v.w;
        }
    }
}

extern "C" void kernel_launch(void* const* d_in, const int* in_sizes, int n_in,
                              void* d_out, int out_size, void* d_ws, size_t ws_size,
                              hipStream_t stream) {
    const float* inp = (const float*)d_in[0];
    const float* w   = (const float*)d_in[1];
    float* outq  = (float*)d_out;
    float* outi  = outq + (size_t)VQ_B * VQ_D * VQ_T;   // indices appended flat

    float*    wnorm = (float*)d_ws;                     // [1024]
    float*    xnorm = wnorm + VQ_K;                     // [65536]
    _Float16* Wh    = (_Float16*)(xnorm + VQ_B * VQ_T); // [1024*256]
    _Float16* Wl    = Wh + (size_t)VQ_K * VQ_D;
    _Float16* Xh    = Wl + (size_t)VQ_K * VQ_D;         // [65536*256], chunk layout
    _Float16* Xl    = Xh + (size_t)VQ_B * VQ_T * VQ_D;
    // total ws use: ~68.4 MB

    vq_prep_kernel<<<dim3(512 + VQ_K / 16), dim3(256), 0, stream>>>(
        inp, w, Xh, Xl, xnorm, wnorm, Wh, Wl);
    vq_mfma_kernel<<<dim3(VQ_B * (VQ_T / 128)), dim3(256), 0, stream>>>(
        Wh, Wl, Xh, Xl, wnorm, xnorm, w, outq, outi);
}